// Round 12
// baseline (169.510 us; speedup 1.0000x reference)
//
#include <hip/hip_runtime.h>

// Depthwise 4x4 FIR blur, pad (2,2)/(2,2), NCHW fp32.
// x: [16,256,128,128] -> out: [16,256,129,129]
//
// Register-streaming kernel, NO barriers, NO global_load_lds, NO LDS input
// staging. Block = 1 image (256 thr, 4 waves). Thread = out cols 4g-2..4g+1
// (g=tid&31) of a 16-row strip (c=tid>>5). Per row ONE dense float4 load
// (wave instr = two contiguous 512B rows); left-neighbor float4 via
// __shfl_up(.,1,32). 8-slot register ring, statically unrolled 16 iters,
// exact tail-counted vmcnt (WAITV(5) steady; never 0) -- the compiler can't
// sink the prefetch (asm memory barriers pin it). Stores bounce through a
// wave-local LDS row buffer -> dense dword flush (R8-proven). Edge cols
// 126..128 via a per-wave LDS strip of g==31's float4s, computed once after
// the loop (removes all edge FMAs from the hot loop).

#define WAITV(NSTR) do {                                                     \
        asm volatile("s_waitcnt vmcnt(" NSTR ")" ::: "memory");              \
        __builtin_amdgcn_sched_barrier(0);                                   \
    } while (0)
#define WAITL() do {                                                         \
        asm volatile("s_waitcnt lgkmcnt(0)" ::: "memory");                   \
        __builtin_amdgcn_sched_barrier(0);                                   \
    } while (0)

__global__ __launch_bounds__(256) void blur_rs(
    const float* __restrict__ x,
    const float* __restrict__ kern,
    float* __restrict__ out)
{
    // obuf: 4 waves x 2 halves x 132 floats; estrip: 4 waves x 36 rows x 4
    __shared__ __align__(16) float sm[4 * 264 + 4 * 144];

    const int tid  = threadIdx.x;
    const int wv   = tid >> 6;       // wave 0..3 (rows 32wv..32wv+31)
    const int lane = tid & 63;
    const int h    = lane >> 5;      // half: strip 2wv+h
    const int g    = lane & 31;      // col group: out cols 4g-2..4g+1
    const int c    = tid >> 5;       // strip 0..7: out rows 16c..16c+15
    const bool lv  = (g >= 1);

    const int bid = blockIdx.x;
    const int img = ((bid & 7) << 9) | (bid >> 3);   // XCD swizzle, 4096=8*512

    const float* __restrict__ xi = x + (size_t)img * 16384;
    float* __restrict__ oi = out + (size_t)img * 16641;

    float w[4][4];
#pragma unroll
    for (int p = 0; p < 4; ++p)
#pragma unroll
        for (int d = 0; d < 4; ++d)
            w[p][d] = kern[4 * p + d];

    float* const obuf   = &sm[wv * 264 + h * 132];
    float* const estrip = &sm[1056 + wv * 144];
    const float* const pb0 = xi + 4 * g;

    // ring: RB[j&7] = input row (16c-2+j) cols 4g..4g+3;
    //       RA[j&3] = cols 4g-4..4g-1 (shfl from RB, zero for g==0)
    float4 RB[8], RA[4];

#define LOADJ(J) do {                                                        \
        int v_ = 16 * c - 2 + (J);                                           \
        v_ = v_ < 0 ? 0 : (v_ > 127 ? 127 : v_);   /* clamp = dummy */       \
        RB[(J) & 7] = *(const float4*)(pb0 + 128 * v_);                      \
    } while (0)

#define ZROW(J) do {                                                         \
        const bool ok_ = (unsigned)(16 * c - 2 + (J)) < 128u;                \
        float4& b_ = RB[(J) & 7];                                            \
        b_.x = ok_ ? b_.x : 0.f; b_.y = ok_ ? b_.y : 0.f;                    \
        b_.z = ok_ ? b_.z : 0.f; b_.w = ok_ ? b_.w : 0.f;                    \
    } while (0)

#define MKRA(J) do {                                                         \
        const float4& s_ = RB[(J) & 7];                                      \
        float4 t_;                                                           \
        t_.x = __shfl_up(s_.x, 1, 32); t_.y = __shfl_up(s_.y, 1, 32);        \
        t_.z = __shfl_up(s_.z, 1, 32); t_.w = __shfl_up(s_.w, 1, 32);        \
        t_.x = lv ? t_.x : 0.f; t_.y = lv ? t_.y : 0.f;                      \
        t_.z = lv ? t_.z : 0.f; t_.w = lv ? t_.w : 0.f;                      \
        RA[(J) & 3] = t_;                                                    \
    } while (0)

#define ESTAGE(J) do {                                                       \
        if (g == 31)                                                         \
            *(float4*)&estrip[(h * 16 + (J)) * 4] = RB[(J) & 7];             \
    } while (0)

#define FMA4(A, B, P) do {                                                   \
        o0 = fmaf((A).x, w[P][0], o0);                                       \
        o0 = fmaf((A).y, w[P][1], o0);                                       \
        o0 = fmaf((A).z, w[P][2], o0);                                       \
        o0 = fmaf((A).w, w[P][3], o0);                                       \
        o1 = fmaf((A).y, w[P][0], o1);                                       \
        o1 = fmaf((A).z, w[P][1], o1);                                       \
        o1 = fmaf((A).w, w[P][2], o1);                                       \
        o1 = fmaf((B).x, w[P][3], o1);                                       \
        o2 = fmaf((A).z, w[P][0], o2);                                       \
        o2 = fmaf((A).w, w[P][1], o2);                                       \
        o2 = fmaf((B).x, w[P][2], o2);                                       \
        o2 = fmaf((B).y, w[P][3], o2);                                       \
        o3 = fmaf((A).w, w[P][0], o3);                                       \
        o3 = fmaf((B).x, w[P][1], o3);                                       \
        o3 = fmaf((B).y, w[P][2], o3);                                       \
        o3 = fmaf((B).z, w[P][3], o3);                                       \
    } while (0)

    // compute out row 16c+I, bounce to obuf, dense flush (4 store instrs)
#define CF(I) do {                                                           \
        float o0 = 0.f, o1 = 0.f, o2 = 0.f, o3 = 0.f;                        \
        FMA4(RA[(I) & 3],       RB[(I) & 7],       0);                       \
        FMA4(RA[((I) + 1) & 3], RB[((I) + 1) & 7], 1);                       \
        FMA4(RA[((I) + 2) & 3], RB[((I) + 2) & 7], 2);                       \
        FMA4(RA[((I) + 3) & 3], RB[((I) + 3) & 7], 3);                       \
        *(float4*)&obuf[4 * g] = make_float4(o0, o1, o2, o3);                \
        WAITL();                                                             \
        float* po_ = oi + (16 * c + (I)) * 129;                              \
        po_[g]      = obuf[2 + g];                                           \
        po_[g + 32] = obuf[34 + g];                                          \
        po_[g + 64] = obuf[66 + g];                                          \
        if (g < 30) po_[g + 96] = obuf[98 + g];                              \
        __builtin_amdgcn_sched_barrier(0);                                   \
    } while (0)

    // ---- prologue: 5 loads in flight ----
    LOADJ(0); LOADJ(1); LOADJ(2); LOADJ(3); LOADJ(4);
    WAITV("1");                       // j0..j3 arrived (j4 in flight)
    ZROW(0); ZROW(1);                 // rows -2,-1 (c==0) -> zero
    MKRA(0); MKRA(1); MKRA(2); MKRA(3);
    ESTAGE(0); ESTAGE(1); ESTAGE(2); ESTAGE(3);
    CF(0);
    LOADJ(5);

    // ---- steady: per iter 4 stores + 1 load; WAITV(5) = prev iter's ops ->
    // target load (issued 2 iters back) retired, newest load stays in flight
#define STEP(I) do {                                                         \
        WAITV("5");                                                          \
        MKRA((I) + 3); ESTAGE((I) + 3);                                      \
        CF(I);                                                               \
        LOADJ((I) + 5);                                                      \
    } while (0)

    STEP(1);  STEP(2);  STEP(3);  STEP(4);  STEP(5);  STEP(6);  STEP(7);
    STEP(8);  STEP(9);  STEP(10); STEP(11); STEP(12); STEP(13);

    WAITV("5"); MKRA(17); ESTAGE(17); CF(14);            // j=18 still in flight
    WAITV("4"); ZROW(18); MKRA(18); ESTAGE(18); CF(15);  // j=18 (row128) zeroed

    // ---- out row 128 (c==7): window rows 126,127 (w rows 0,1); j=16,17 ----
    if (c == 7) {
        float o0 = 0.f, o1 = 0.f, o2 = 0.f, o3 = 0.f;
        FMA4(RA[0], RB[0], 0);        // j=16 = row 126
        FMA4(RA[1], RB[1], 1);        // j=17 = row 127
        *(float4*)&obuf[4 * g] = make_float4(o0, o1, o2, o3);
        WAITL();
        float* po_ = oi + 128 * 129;
        po_[g]      = obuf[2 + g];
        po_[g + 32] = obuf[34 + g];
        po_[g + 64] = obuf[66 + g];
        if (g < 30) po_[g + 96] = obuf[98 + g];
    }

    // ---- edge cols 126..128 (wave-local; estrip[k] = img row 32wv-2+k) ----
    WAITL();
    {
        const int r2 = g;             // out row 32wv+r2, k = r2..r2+3
        float e = 0.f, e2 = 0.f;
#pragma unroll
        for (int p = 0; p < 4; ++p) {
            const float4 v = *(const float4*)&estrip[(r2 + p) * 4];
            const float s126 = v.x*w[p][0] + v.y*w[p][1] + v.z*w[p][2] + v.w*w[p][3];
            const float s127 = v.y*w[p][0] + v.z*w[p][1] + v.w*w[p][2];
            e  += h ? s127 : s126;
            e2 += v.z*w[p][0] + v.w*w[p][1];
        }
        float* pe = oi + (size_t)(32 * wv + r2) * 129 + 126;
        pe[h] = e;                    // col 126 (h=0) / 127 (h=1)
        if (h == 0) pe[2] = e2;       // col 128
    }
    // out row 128 edge (rows 126,127 = estrip k=32,33; w==3 only)
    if (wv == 3 && lane < 3) {
        float e = 0.f;
#pragma unroll
        for (int p = 0; p < 2; ++p) {
            const float4 v = *(const float4*)&estrip[(32 + p) * 4];
            const float s0 = v.x*w[p][0] + v.y*w[p][1] + v.z*w[p][2] + v.w*w[p][3];
            const float s1 = v.y*w[p][0] + v.z*w[p][1] + v.w*w[p][2];
            const float s2 = v.z*w[p][0] + v.w*w[p][1];
            e += (lane == 0) ? s0 : ((lane == 1) ? s1 : s2);
        }
        oi[128 * 129 + 126 + lane] = e;
    }

#undef LOADJ
#undef ZROW
#undef MKRA
#undef ESTAGE
#undef FMA4
#undef CF
#undef STEP
}

extern "C" void kernel_launch(void* const* d_in, const int* in_sizes, int n_in,
                              void* d_out, int out_size, void* d_ws, size_t ws_size,
                              hipStream_t stream) {
    const float* x    = (const float*)d_in[0];
    const float* kern = (const float*)d_in[1];
    float* out        = (float*)d_out;

    dim3 grid(4096), block(256);     // one block per image
    hipLaunchKernelGGL(blur_rs, grid, block, 0, stream, x, kern, out);
}

// Round 13
// 124.511 us; speedup vs baseline: 1.3614x; 1.3614x over previous
//
#include <hip/hip_runtime.h>

// Depthwise 4x4 FIR blur, pad (2,2)/(2,2), NCHW fp32.
// x: [16,256,128,128] -> out: [16,256,129,129]
//
// Dense deep-MLP register kernel (copy-ubench shape): NO LDS, NO barriers.
// Thread = (img, 8-row block rb, col group g): out cols 4g-2..4g+1, rows
// 8rb..8rb+7 (rb==15 also row 128). ALL 11 window-row float4 loads issued
// up-front (dense: half-wave = 512B contiguous per instruction), one wait,
// then straight-line FMA. Left-neighbor vector via __shfl_up(.,1,32);
// row pad zero-masked on j=0,1,10 only; col pad via lv; edge cols 126..128
// folded into g==31 lanes inline.

__global__ __launch_bounds__(256) void blur_deep(
    const float* __restrict__ x,
    const float* __restrict__ kern,
    float* __restrict__ out)
{
    const int tid = threadIdx.x;
    const int bid = blockIdx.x;
    // bijective XCD swizzle: 8192 blocks = 8 XCDs x 1024
    const int wk  = ((bid & 7) << 10) | (bid >> 3);
    const int img = wk >> 1;
    const int s   = wk & 1;          // image half
    const int rb  = 8 * s + (tid >> 5);   // row block 0..15: rows 8rb..8rb+7
    const int r0  = rb << 3;
    const int g   = tid & 31;        // col group: out cols 4g-2..4g+1
    const bool lv = (g >= 1);

    const float* __restrict__ xi = x + (size_t)img * 16384;
    float* __restrict__ oi = out + (size_t)img * 16641;

    float w[4][4];
#pragma unroll
    for (int p = 0; p < 4; ++p)
#pragma unroll
        for (int d = 0; d < 4; ++d)
            w[p][d] = kern[4 * p + d];

    const float* const pb0 = xi + 4 * g;

    // ---- issue ALL 11 dense loads up-front ----
    // RB[j] = input row (r0-2+j), cols 4g..4g+3 (clamped dummy rows at pad)
    float4 RB[11];
#pragma unroll
    for (int j = 0; j < 11; ++j) {
        int v = r0 - 2 + j;
        v = v < 0 ? 0 : (v > 127 ? 127 : v);
        RB[j] = *(const float4*)(pb0 + 128 * v);
    }
    __builtin_amdgcn_sched_barrier(0);   // pin: no sinking into compute

    // row-pad mask: only j=0,1 (rb==0) and j=10 (rb==15) can be OOB
#define ZMASK(J) do {                                                        \
        const bool ok_ = (unsigned)(r0 - 2 + (J)) < 128u;                    \
        RB[J].x = ok_ ? RB[J].x : 0.f; RB[J].y = ok_ ? RB[J].y : 0.f;        \
        RB[J].z = ok_ ? RB[J].z : 0.f; RB[J].w = ok_ ? RB[J].w : 0.f;        \
    } while (0)
    ZMASK(0); ZMASK(1); ZMASK(10);

    // left-neighbor vector: RA[j&3] = row (r0-2+j), cols 4g-4..4g-1
    float4 RA[4];
#define MKRA(J) do {                                                         \
        const float4 s_ = RB[J];                                             \
        float4 t_;                                                           \
        t_.x = __shfl_up(s_.x, 1, 32); t_.y = __shfl_up(s_.y, 1, 32);        \
        t_.z = __shfl_up(s_.z, 1, 32); t_.w = __shfl_up(s_.w, 1, 32);        \
        t_.x = lv ? t_.x : 0.f; t_.y = lv ? t_.y : 0.f;                      \
        t_.z = lv ? t_.z : 0.f; t_.w = lv ? t_.w : 0.f;                      \
        RA[(J) & 3] = t_;                                                    \
    } while (0)

#define FMA4(A, B, P) do {                                                   \
        o0 = fmaf((A).x, w[P][0], o0);                                       \
        o0 = fmaf((A).y, w[P][1], o0);                                       \
        o0 = fmaf((A).z, w[P][2], o0);                                       \
        o0 = fmaf((A).w, w[P][3], o0);                                       \
        o1 = fmaf((A).y, w[P][0], o1);                                       \
        o1 = fmaf((A).z, w[P][1], o1);                                       \
        o1 = fmaf((A).w, w[P][2], o1);                                       \
        o1 = fmaf((B).x, w[P][3], o1);                                       \
        o2 = fmaf((A).z, w[P][0], o2);                                       \
        o2 = fmaf((A).w, w[P][1], o2);                                       \
        o2 = fmaf((B).x, w[P][2], o2);                                       \
        o2 = fmaf((B).y, w[P][3], o2);                                       \
        o3 = fmaf((A).w, w[P][0], o3);                                       \
        o3 = fmaf((B).x, w[P][1], o3);                                       \
        o3 = fmaf((B).y, w[P][2], o3);                                       \
        o3 = fmaf((B).z, w[P][3], o3);                                       \
    } while (0)

    // out row r0+I: window j = I..I+3; edge cols from RB (=cols 124..127
    // when g==31); store strided (R6-proven)
#define ROW(I) do {                                                          \
        float o0 = 0.f, o1 = 0.f, o2 = 0.f, o3 = 0.f;                        \
        FMA4(RA[(I) & 3],       RB[(I)],     0);                             \
        FMA4(RA[((I) + 1) & 3], RB[(I) + 1], 1);                             \
        FMA4(RA[((I) + 2) & 3], RB[(I) + 2], 2);                             \
        FMA4(RA[((I) + 3) & 3], RB[(I) + 3], 3);                             \
        float* po_ = oi + (size_t)(r0 + (I)) * 129 + 4 * g - 2;              \
        if (lv) { po_[0] = o0; po_[1] = o1; }                                \
        po_[2] = o2;                                                         \
        po_[3] = o3;                                                         \
        if (g == 31) {                                                       \
            float e0 = 0.f, e1 = 0.f, e2 = 0.f;                              \
            _Pragma("unroll")                                                \
            for (int p_ = 0; p_ < 4; ++p_) {                                 \
                const float4 v_ = RB[(I) + p_];                              \
                e0 = fmaf(v_.x, w[p_][0], e0);                               \
                e0 = fmaf(v_.y, w[p_][1], e0);                               \
                e0 = fmaf(v_.z, w[p_][2], e0);                               \
                e0 = fmaf(v_.w, w[p_][3], e0);                               \
                e1 = fmaf(v_.y, w[p_][0], e1);                               \
                e1 = fmaf(v_.z, w[p_][1], e1);                               \
                e1 = fmaf(v_.w, w[p_][2], e1);                               \
                e2 = fmaf(v_.z, w[p_][0], e2);                               \
                e2 = fmaf(v_.w, w[p_][1], e2);                               \
            }                                                                \
            po_[4] = e0; po_[5] = e1; po_[6] = e2;  /* cols 126..128 */      \
        }                                                                    \
    } while (0)

    MKRA(0); MKRA(1); MKRA(2);
    MKRA(3);  ROW(0);
    MKRA(4);  ROW(1);
    MKRA(5);  ROW(2);
    MKRA(6);  ROW(3);
    MKRA(7);  ROW(4);
    MKRA(8);  ROW(5);
    MKRA(9);  ROW(6);
    MKRA(10); ROW(7);

    // out row 128 (rb==15): window rows 126,127 = j8,j9 (+2 zero pad rows).
    // RA ring now holds j8 at [0], j9 at [1].
    if (rb == 15) {
        float o0 = 0.f, o1 = 0.f, o2 = 0.f, o3 = 0.f;
        FMA4(RA[0], RB[8], 0);
        FMA4(RA[1], RB[9], 1);
        float* po_ = oi + (size_t)128 * 129 + 4 * g - 2;
        if (lv) { po_[0] = o0; po_[1] = o1; }
        po_[2] = o2;
        po_[3] = o3;
        if (g == 31) {
            float e0 = 0.f, e1 = 0.f, e2 = 0.f;
#pragma unroll
            for (int p_ = 0; p_ < 2; ++p_) {
                const float4 v_ = RB[8 + p_];
                e0 = fmaf(v_.x, w[p_][0], e0);
                e0 = fmaf(v_.y, w[p_][1], e0);
                e0 = fmaf(v_.z, w[p_][2], e0);
                e0 = fmaf(v_.w, w[p_][3], e0);
                e1 = fmaf(v_.y, w[p_][0], e1);
                e1 = fmaf(v_.z, w[p_][1], e1);
                e1 = fmaf(v_.w, w[p_][2], e1);
                e2 = fmaf(v_.z, w[p_][0], e2);
                e2 = fmaf(v_.w, w[p_][1], e2);
            }
            po_[4] = e0; po_[5] = e1; po_[6] = e2;
        }
    }

#undef ZMASK
#undef MKRA
#undef FMA4
#undef ROW
}

extern "C" void kernel_launch(void* const* d_in, const int* in_sizes, int n_in,
                              void* d_out, int out_size, void* d_ws, size_t ws_size,
                              hipStream_t stream) {
    const float* x    = (const float*)d_in[0];
    const float* kern = (const float*)d_in[1];
    float* out        = (float*)d_out;

    // 4096 images * 2 halves * (8 row-blocks x 32 col-groups) = 8192 x 256
    dim3 grid(8192), block(256);
    hipLaunchKernelGGL(blur_deep, grid, block, 0, stream, x, kern, out);
}

// Round 14
// 117.578 us; speedup vs baseline: 1.4417x; 1.0590x over previous
//
#include <hip/hip_runtime.h>

// Depthwise 4x4 FIR blur, pad (2,2)/(2,2), NCHW fp32.
// x: [16,256,128,128] -> out: [16,256,129,129]
//
// R8 champion kernel (109.7 us) with ONE change: output stores are
// NONTEMPORAL (no L2/L3 write-allocate). Theory: streaming writes were
// evicting the 248.6 MB input from the 256 MB L3 between timed replays;
// nt stores keep input L3-resident -> read stream becomes L3-served,
// HBM stream approaches write-only (~7 TB/s fill-calibrated).
//
// Block = half image (64 output rows; s==1 also row 128), 512 threads.
// Stage all 66 valid input rows (33 x 1KB global_load_lds pairs) + zero pad
// rows + zero-row, ONE __syncthreads, then compute. Thread = 4 output cols
// (g=tid&31) x 4 rows (c=tid>>5) via ds_read_b128 register ring. Stores
// bounce through a wave-local LDS row buffer -> dense nt dword flush.

__global__ __launch_bounds__(512) void blur_half3_nt(
    const float* __restrict__ x,
    const float* __restrict__ kern,
    float* __restrict__ out)
{
    // input rows: slots 0..67 (+ zero-row slot 68) = 8832 floats;
    // out bounce: 8 waves x 2 halves x 132 floats = 2112 floats. 43.8 KB.
    __shared__ __align__(16) float lds[69 * 128 + 8 * 264];

    const int tid  = threadIdx.x;
    const int bid  = blockIdx.x;
    // bijective XCD swizzle: 8192 blocks = 8 XCDs x 1024
    const int wk   = ((bid & 7) << 10) | (bid >> 3);
    const int img  = wk >> 1;
    const int s    = wk & 1;         // half: out rows [64s, 64s+64)
    const int wv   = tid >> 6;
    const int lane = tid & 63;

    const float* __restrict__ xi = x + (size_t)img * (128 * 128);
    float* __restrict__ oi = out + (size_t)img * (129 * 129);

    // ---- stage: pair p = LDS slots (2p, 2p+1) = input rows 64s-2+2p, +1.
    // Valid pairs: s==0 -> p=1..33 (rows 0..65); s==1 -> p=0..32 (rows 62..127).
    const int P0 = s ? 0 : 1;
    const int P1 = s ? 32 : 33;
    for (int p = P0 + wv; p <= P1; p += 8) {
        const int row = 64 * s - 2 + 2 * p;
        const float* src = xi + (size_t)row * 128 + (lane << 2);
        const float* dst = &lds[p * 256];
        __builtin_amdgcn_global_load_lds(
            (const __attribute__((address_space(1))) unsigned int*)src,
            (__attribute__((address_space(3))) unsigned int*)dst, 16, 0, 0);
    }
    // zero pad rows + zero-row (disjoint from staged slots)
    if (tid < 256) {
        if (s) lds[8448 + tid] = 0.0f;   // slots 66,67 (rows 128,129)
        else   lds[tid]        = 0.0f;   // slots 0,1   (rows -2,-1)
    } else if (tid < 384) {
        lds[8448 + tid] = 0.0f;          // 8704..8831 = slot 68 (zero-row)
    }

    // 4x4 weights; uniform -> SGPRs
    float w[4][4];
#pragma unroll
    for (int p = 0; p < 4; ++p)
#pragma unroll
        for (int q = 0; q < 4; ++q)
            w[p][q] = kern[4 * p + q];

    __syncthreads();

    // ---- compute ----
    const int c  = tid >> 5;         // row subchunk 0..15 (4 rows each)
    const int g  = tid & 31;         // col group: out cols 4g-2 .. 4g+1
    const bool lv = (g >= 1);
    const float* const zrow = &lds[68 * 128];
    // wave-local out bounce buffer: [wv][half][132]; col j at idx j+2
    float* const obuf = &lds[69 * 128 + wv * 264 + (c & 1) * 132];

    float xv[4][8];

    // out row i = 64s+4c+j window = slots 4c+j .. 4c+j+3; a = cols 4g-4..4g-1
    // (zero-row for g==0), b = cols 4g..4g+3. Both reads unconditional.
#define LLOAD(S, KK) do {                                                    \
        const float* pb_ = &lds[(4 * c + (KK)) * 128 + 4 * g];               \
        const float* pa_ = lv ? (pb_ - 4) : zrow;                            \
        float4 a_ = *(const float4*)pa_;                                     \
        float4 b_ = *(const float4*)pb_;                                     \
        xv[S][0] = a_.x; xv[S][1] = a_.y; xv[S][2] = a_.z; xv[S][3] = a_.w;  \
        xv[S][4] = b_.x; xv[S][5] = b_.y; xv[S][6] = b_.z; xv[S][7] = b_.w;  \
    } while (0)

#define ACCP(S, P) do {                                                      \
        o0 = fmaf(xv[S][0], w[P][0], o0);                                    \
        o1 = fmaf(xv[S][1], w[P][0], o1);                                    \
        o2 = fmaf(xv[S][2], w[P][0], o2);                                    \
        o3 = fmaf(xv[S][3], w[P][0], o3);                                    \
        o0 = fmaf(xv[S][1], w[P][1], o0);                                    \
        o1 = fmaf(xv[S][2], w[P][1], o1);                                    \
        o2 = fmaf(xv[S][3], w[P][1], o2);                                    \
        o3 = fmaf(xv[S][4], w[P][1], o3);                                    \
        o0 = fmaf(xv[S][2], w[P][2], o0);                                    \
        o1 = fmaf(xv[S][3], w[P][2], o1);                                    \
        o2 = fmaf(xv[S][4], w[P][2], o2);                                    \
        o3 = fmaf(xv[S][5], w[P][2], o3);                                    \
        o0 = fmaf(xv[S][3], w[P][3], o0);                                    \
        o1 = fmaf(xv[S][4], w[P][3], o1);                                    \
        o2 = fmaf(xv[S][5], w[P][3], o2);                                    \
        o3 = fmaf(xv[S][6], w[P][3], o3);                                    \
    } while (0)

    // edge cols 126..128 for g==31 (xv[.][4..7] = input cols 124..127)
#define XROW(S, P) do {                                                      \
        e0 = fmaf(xv[S][4], w[P][0], e0);                                    \
        e0 = fmaf(xv[S][5], w[P][1], e0);                                    \
        e0 = fmaf(xv[S][6], w[P][2], e0);                                    \
        e0 = fmaf(xv[S][7], w[P][3], e0);                                    \
        e1 = fmaf(xv[S][5], w[P][0], e1);                                    \
        e1 = fmaf(xv[S][6], w[P][1], e1);                                    \
        e1 = fmaf(xv[S][7], w[P][2], e1);                                    \
        e2 = fmaf(xv[S][6], w[P][0], e2);                                    \
        e2 = fmaf(xv[S][7], w[P][1], e2);                                    \
    } while (0)

    // CS: compute row 64s+4c+J, bounce to obuf, flush densely (nontemporal).
#define CS(SA, SB, SC, SD, J) do {                                           \
        float o0 = 0.f, o1 = 0.f, o2 = 0.f, o3 = 0.f;                        \
        ACCP(SA, 0); ACCP(SB, 1); ACCP(SC, 2); ACCP(SD, 3);                  \
        *(float4*)&obuf[4 * g] = make_float4(o0, o1, o2, o3);                \
        if (g == 31) {                                                       \
            float e0 = 0.f, e1 = 0.f, e2 = 0.f;                              \
            XROW(SA, 0); XROW(SB, 1); XROW(SC, 2); XROW(SD, 3);              \
            *(float2*)&obuf[128] = make_float2(e0, e1);  /* cols 126,127 */  \
            obuf[130] = e2;                              /* col  128     */  \
        }                                                                    \
        asm volatile("s_waitcnt lgkmcnt(0)" ::: "memory");                   \
        __builtin_amdgcn_sched_barrier(0);                                   \
        {                                                                    \
            float* po_ = oi + (size_t)(64 * s + 4 * c + (J)) * 129;          \
            _Pragma("unroll")                                                \
            for (int k_ = 0; k_ < 4; ++k_)                                   \
                __builtin_nontemporal_store(obuf[2 + g + 32 * k_],           \
                                            &po_[g + 32 * k_]);              \
            if (g == 0)                                                      \
                __builtin_nontemporal_store(obuf[130], &po_[128]);           \
        }                                                                    \
    } while (0)

    {
        LLOAD(0, 0); LLOAD(1, 1); LLOAD(2, 2); LLOAD(3, 3);
        CS(0, 1, 2, 3, 0); LLOAD(0, 4);
        CS(1, 2, 3, 0, 1); LLOAD(1, 5);
        CS(2, 3, 0, 1, 2); LLOAD(2, 6);
        CS(3, 0, 1, 2, 3);
        if (s == 1 && c == 15) {                 // out row 128: slots 64..67
            LLOAD(3, 7);
            CS(0, 1, 2, 3, 4);
        }
    }

#undef LLOAD
#undef ACCP
#undef XROW
#undef CS
}

extern "C" void kernel_launch(void* const* d_in, const int* in_sizes, int n_in,
                              void* d_out, int out_size, void* d_ws, size_t ws_size,
                              hipStream_t stream) {
    const float* x    = (const float*)d_in[0];
    const float* kern = (const float*)d_in[1];
    float* out        = (float*)d_out;

    // 4096 images * 2 halves = 8192 blocks
    dim3 grid(8192), block(512);
    hipLaunchKernelGGL(blur_half3_nt, grid, block, 0, stream, x, kern, out);
}